// Round 13
// baseline (1264.110 us; speedup 1.0000x reference)
//
#include <hip/hip_runtime.h>
#include <hip/hip_bf16.h>

#define DMODEL 512
#define NB 8
#define VOCABSZ 2048
#define MEL 80
#define DIN 1024
#define NSTATE 16
#define BATCH 4
#define TIN 2048
#define LL1 1024
#define LSEQ 512
#define MROWS (BATCH*LSEQ)    // 2048
#define M1ROWS (BATCH*LL1)    // 4096
#define NCHUNK 16
#define LCHUNK 32

typedef unsigned short u16;
typedef unsigned int   u32;
typedef __attribute__((ext_vector_type(8))) short short8;
typedef __attribute__((ext_vector_type(4))) float f32x4;

__device__ __forceinline__ float bf2f(u16 v) { return __uint_as_float(((u32)v) << 16); }
__device__ __forceinline__ u16 f2bf(float f) {
    u32 u = __float_as_uint(f);
    return (u16)((u + 0x7fffu + ((u >> 16) & 1u)) >> 16);
}
__device__ __forceinline__ float gelu_exact(float v) {
    return 0.5f * v * (1.0f + erff(v * 0.70710678118654752f));
}
__device__ __forceinline__ float silu_f(float v) { return v / (1.0f + __expf(-v)); }
__device__ __forceinline__ float softplus_f(float v) { return v > 20.f ? v : log1pf(__expf(v)); }

// ---------------------------------------------------------------------------
// bf16 MFMA GEMM, BK=64 as two 32-wide sub-tiles (R12-proven).
// EPI: 0 none, 1 +bias, 2 gelu(+bias), 4 +=Cf residual,
//      7 fused-RMS row-scale (sc from A fragments)
// ---------------------------------------------------------------------------
template<int WM, int WN, int MR, int NR, int EPI, int SPLITK>
__global__ __launch_bounds__(WM*WN*64) void gemm3_bf16(
    const u16* __restrict__ A, int lda,
    const u16* __restrict__ BT, int ldb,
    const float* __restrict__ bias,
    float* __restrict__ Cf, u16* __restrict__ Cb, int ldc,
    int K, int zstride)
{
    constexpr int BM = WM * MR * 16;
    constexpr int BN = WN * NR * 16;
    constexpr int NT = WM * WN * 64;
    constexpr int LA = (BM * 4) / NT;
    constexpr int LB = (BN * 4) / NT;
    __shared__ __align__(16) u16 As[2][2 * BM * 32];
    __shared__ __align__(16) u16 Bs[2][2 * BN * 32];
    __shared__ float s_sc[EPI == 7 ? BM : 1];
    const int tid = threadIdx.x;
    const int m0 = blockIdx.y * BM, n0 = blockIdx.x * BN;
    const int lane = tid & 63;
    const int wave = tid >> 6;
    const int wm = wave / WN, wn = wave % WN;
    const int lr = lane & 15, lk = lane >> 4;

    int kt0 = 0, kend = K;
    if (SPLITK > 1) {
        const int kb = K / SPLITK;
        kt0 = blockIdx.z * kb;
        kend = kt0 + kb;
        Cf += (size_t)blockIdx.z * zstride;
    }

    f32x4 acc[MR][NR];
#pragma unroll
    for (int m = 0; m < MR; ++m)
#pragma unroll
        for (int n = 0; n < NR; ++n) acc[m][n] = (f32x4){0.f, 0.f, 0.f, 0.f};
    float ssq[MR];
#pragma unroll
    for (int m = 0; m < MR; ++m) ssq[m] = 0.f;

    auto stage = [&](int buf, int kt) {
#pragma unroll
        for (int h = 0; h < 2; ++h) {
#pragma unroll
            for (int c = 0; c < LA; ++c) {
                int idx = c * NT + tid;
                const u16* src = A + (size_t)(m0 + (idx >> 2)) * lda + kt + h * 32 + (idx & 3) * 8;
                __builtin_amdgcn_global_load_lds(
                    (const __attribute__((address_space(1))) void*)src,
                    (__attribute__((address_space(3))) void*)&As[buf][h * BM * 32 + idx * 8], 16, 0, 0);
            }
#pragma unroll
            for (int c = 0; c < LB; ++c) {
                int idx = c * NT + tid;
                const u16* src = BT + (size_t)(n0 + (idx >> 2)) * ldb + kt + h * 32 + (idx & 3) * 8;
                __builtin_amdgcn_global_load_lds(
                    (const __attribute__((address_space(1))) void*)src,
                    (__attribute__((address_space(3))) void*)&Bs[buf][h * BN * 32 + idx * 8], 16, 0, 0);
            }
        }
    };

    stage(0, kt0);
    __syncthreads();
    int cur = 0;
    for (int kt = kt0; kt < kend; kt += 64) {
        if (kt + 64 < kend) stage(cur ^ 1, kt + 64);
        short8 a0[MR], a1[MR], b0[NR], b1[NR];
#pragma unroll
        for (int m = 0; m < MR; ++m) {
            a0[m] = *(const short8*)&As[cur][((wm * MR + m) * 16 + lr) * 32 + lk * 8];
            a1[m] = *(const short8*)&As[cur][BM * 32 + ((wm * MR + m) * 16 + lr) * 32 + lk * 8];
        }
#pragma unroll
        for (int n = 0; n < NR; ++n) {
            b0[n] = *(const short8*)&Bs[cur][((wn * NR + n) * 16 + lr) * 32 + lk * 8];
            b1[n] = *(const short8*)&Bs[cur][BN * 32 + ((wn * NR + n) * 16 + lr) * 32 + lk * 8];
        }
        if (EPI == 7 && wn == 0) {
#pragma unroll
            for (int m = 0; m < MR; ++m)
#pragma unroll
                for (int j = 0; j < 8; ++j) {
                    float v0 = bf2f((u16)a0[m][j]);
                    float v1 = bf2f((u16)a1[m][j]);
                    ssq[m] = fmaf(v0, v0, ssq[m]);
                    ssq[m] = fmaf(v1, v1, ssq[m]);
                }
        }
#pragma unroll
        for (int m = 0; m < MR; ++m)
#pragma unroll
            for (int n = 0; n < NR; ++n) {
                acc[m][n] = __builtin_amdgcn_mfma_f32_16x16x32_bf16(a0[m], b0[n], acc[m][n], 0, 0, 0);
                acc[m][n] = __builtin_amdgcn_mfma_f32_16x16x32_bf16(a1[m], b1[n], acc[m][n], 0, 0, 0);
            }
        __syncthreads();
        cur ^= 1;
    }

    if (EPI == 7) {
        if (wn == 0) {
#pragma unroll
            for (int m = 0; m < MR; ++m) {
                float ss = ssq[m];
                ss += __shfl_xor(ss, 16);
                ss += __shfl_xor(ss, 32);
                if (lk == 0)
                    s_sc[(wm * MR + m) * 16 + lr] = rsqrtf(ss * (1.f / 512.f) + 1e-5f);
            }
        }
        __syncthreads();
    }

#pragma unroll
    for (int m = 0; m < MR; ++m) {
#pragma unroll
        for (int n = 0; n < NR; ++n) {
#pragma unroll
            for (int r = 0; r < 4; ++r) {
                const int lrow = (wm * MR + m) * 16 + lk * 4 + r;
                const int row = m0 + lrow;
                const int col = n0 + (wn * NR + n) * 16 + lr;
                float v = acc[m][n][r];
                if (EPI == 1)      v += bias[col];
                else if (EPI == 2) v = gelu_exact(v + bias[col]);
                else if (EPI == 4) v += Cf[(size_t)row * ldc + col];
                else if (EPI == 7) v *= s_sc[lrow];
                if (Cf) Cf[(size_t)row * ldc + col] = v;
                if (Cb) Cb[(size_t)row * ldc + col] = f2bf(v);
            }
        }
    }
}

// ---------------------------------------------------------------------------
// Fused weight prep: all transposes + cast/pads in ONE dispatch (17664 blocks)
// ---------------------------------------------------------------------------
__device__ __forceinline__ void tp_tile(float (*s)[33], const float* __restrict__ in,
                                        u16* __restrict__ out, int R, int C, int tile,
                                        const float* __restrict__ nwp) {
    const int tx = threadIdx.x & 31, ty = threadIdx.x >> 5;
    const int tC = C / 32;
    const int r0 = (tile / tC) * 32, c0 = (tile % tC) * 32;
#pragma unroll
    for (int i = 0; i < 4; ++i)
        s[ty + i * 8][tx] = in[(size_t)(r0 + ty + i * 8) * C + c0 + tx];
    __syncthreads();
    const float nwv = nwp ? nwp[r0 + tx] : 1.f;
#pragma unroll
    for (int i = 0; i < 4; ++i)
        out[(size_t)(c0 + ty + i * 8) * R + r0 + tx] = f2bf(s[tx][ty + i * 8] * nwv);
}

__global__ __launch_bounds__(256) void prep_k(
    const float* __restrict__ hw, u16* __restrict__ hwT,
    const float* __restrict__ xpw, u16* __restrict__ xpwT,
    const float* __restrict__ dpw, u16* __restrict__ dpwT,
    const float* __restrict__ ipw, u16* __restrict__ ipwTa, const float* __restrict__ nw,
    const float* __restrict__ opw, u16* __restrict__ opwTa,
    const float* __restrict__ c1w, u16* __restrict__ c1wb,
    const float* __restrict__ c2w, u16* __restrict__ c2wb)
{
    __shared__ float s[32][33];
    int id = blockIdx.x;
    if (id < 1024) { tp_tile(s, hw, hwT, 512, 2048, id, nullptr); return; }
    id -= 1024;
    if (id < 512) {
        int z = id >> 6, t = id & 63;
        tp_tile(s, xpw + (size_t)z * 65536, xpwT + (size_t)z * 65536, 1024, 64, t, nullptr);
        return;
    }
    id -= 512;
    if (id < 256) {
        int z = id >> 5, t = id & 31;
        tp_tile(s, dpw + (size_t)z * 32768, dpwT + (size_t)z * 32768, 32, 1024, t, nullptr);
        return;
    }
    id -= 256;
    if (id < 8192) {
        int z = id >> 10, t = id & 1023;
        tp_tile(s, ipw + (size_t)z * 1048576, ipwTa + (size_t)z * 1048576, 512, 2048, t, nw + z * DMODEL);
        return;
    }
    id -= 8192;
    if (id < 4096) {
        int z = id >> 9, t = id & 511;
        tp_tile(s, opw + (size_t)z * 524288, opwTa + (size_t)z * 524288, 1024, 512, t, nullptr);
        return;
    }
    id -= 4096;
    if (id < 512) {
        int idx = id * 256 + threadIdx.x;
        int c = idx & 255, r = idx >> 8;
        c1wb[idx] = (c < 240) ? f2bf(c1w[r * 240 + c]) : (u16)0;
        return;
    }
    id -= 512;
    {
        int idx = id * 256 + threadIdx.x;
        c2wb[idx] = f2bf(c2w[idx]);
    }
}

// im2col conv1 -> bf16 (K padded 240->256); also writes out_lens
__global__ void im2col1_k(const float* __restrict__ feats, u16* __restrict__ out,
                          const int* __restrict__ feat_lens, float* __restrict__ lens_out) {
    int idx = blockIdx.x * 256 + threadIdx.x;
    if (blockIdx.x == 0 && threadIdx.x < BATCH) {
        int v = feat_lens[threadIdx.x] / 4;
        if (v < 1) v = 1;
        lens_out[threadIdx.x] = (float)v;
    }
    int c = idx & 255, m = idx >> 8;
    int l1 = m & (LL1 - 1), b = m >> 10;
    float v = 0.f;
    if (c < 240) {
        int ci = c / 3, kk = c - ci * 3;
        int t = 2 * l1 - 1 + kk;
        if (t >= 0 && t < TIN) v = feats[((size_t)b * TIN + t) * MEL + ci];
    }
    out[idx] = f2bf(v);
}

// im2col conv2: bf16 in, bf16 out (2048,1536)
__global__ void im2col2_k(const u16* __restrict__ y1b, u16* __restrict__ out) {
    int idx = blockIdx.x * 256 + threadIdx.x;
    int c = idx % 1536, m = idx / 1536;
    int l = m & (LSEQ - 1), b = m >> 9;
    int ci = c / 3, kk = c - ci * 3;
    int t = 2 * l - 1 + kk;
    out[idx] = (t >= 0 && t < LL1) ? y1b[((size_t)b * LL1 + t) * 512 + ci] : (u16)0;
}

// causal depthwise conv (K=4) + bias + SiLU; bf16 in, bf16 out
__global__ __launch_bounds__(256) void dwconv_silu_k(const u16* __restrict__ xzb,
                                                     const float* __restrict__ cw,
                                                     const float* __restrict__ cb,
                                                     u16* __restrict__ xsb) {
    int d = blockIdx.x * 256 + threadIdx.x;
    int m = blockIdx.y;
    int l = m & (LSEQ - 1);
    int b = m >> 9;
    float acc = cb[d];
    const float4 w4 = *reinterpret_cast<const float4*>(&cw[d * 4]);
    const float wk[4] = {w4.x, w4.y, w4.z, w4.w};
#pragma unroll
    for (int k = 0; k < 4; k++) {
        int t = l - 3 + k;
        if (t >= 0) acc += wk[k] * bf2f(xzb[((size_t)(b * LSEQ + t)) * (2 * DIN) + d]);
    }
    xsb[(size_t)m * DIN + d] = f2bf(silu_f(acc));
}

// ---------------------------------------------------------------------------
// Chunked parallel scan with FUSED dt_proj (delta computed in staging from the
// split-K partials + dpw).  NCHUNK=16, LCHUNK=32 (R5-proven shape).
// PASS0: emit P,Q.  PASS1: <=15-step combine, seeded scan, fused epilogue.
// ---------------------------------------------------------------------------
template<int PASS>
__global__ __launch_bounds__(256) void scan_chunk_k(
    const u16* __restrict__ xsb, const float* __restrict__ part,
    const u16* __restrict__ xzb,
    const u16* __restrict__ dpwT, const float* __restrict__ dpb,
    const float* __restrict__ alog, const float* __restrict__ dsk,
    float* __restrict__ P, float* __restrict__ Q,
    u16* __restrict__ yb)
{
    __shared__ float s_bc[LCHUNK * 32];
    __shared__ float s_dt[LCHUNK * 32];
    __shared__ float s_dl[LCHUNK * 64];
    __shared__ float s_xs[LCHUNK * 64];
    __shared__ float s_z [PASS ? LCHUNK * 64 : 1];

    const int tid  = threadIdx.x;
    const int j    = tid & 3;
    const int dsub = tid >> 2;
    const int d0   = blockIdx.x * 64;
    const int c    = blockIdx.y;
    const int b    = blockIdx.z;
    const int d    = d0 + dsub;
    const size_t rbase = (size_t)b * LSEQ + c * LCHUNK;

    for (int idx = tid; idx < LCHUNK * 32; idx += 256) {
        int t = idx >> 5, cc = idx & 31;
        const size_t o = (rbase + t) * 64 + cc;
        s_dt[idx] = part[o] + part[131072 + o] + part[262144 + o] + part[393216 + o];
        const size_t o2 = o + 32;
        s_bc[idx] = part[o2] + part[131072 + o2] + part[262144 + o2] + part[393216 + o2];
    }
    for (int idx = tid; idx < LCHUNK * 64; idx += 256) {
        int t = idx >> 6, dd = idx & 63;
        s_xs[idx] = bf2f(xsb[(rbase + t) * DIN + d0 + dd]);
        if (PASS) s_z[idx] = bf2f(xzb[(rbase + t) * (2 * DIN) + DIN + d0 + dd]);
    }
    __syncthreads();

    // fused dt_proj: s_dl[t][dd] = softplus(dt[t,:] . dpw[:,d0+dd] + dpb)
    {
        const int dd = tid & 63, tq = tid >> 6;     // 4 threads share each dd
        const u16* wrow = dpwT + (size_t)(d0 + dd) * 32;
        const uint4 w0 = *(const uint4*)&wrow[0];
        const uint4 w1 = *(const uint4*)&wrow[8];
        const uint4 w2 = *(const uint4*)&wrow[16];
        const uint4 w3 = *(const uint4*)&wrow[24];
        const u32 wa[16] = {w0.x, w0.y, w0.z, w0.w, w1.x, w1.y, w1.z, w1.w,
                            w2.x, w2.y, w2.z, w2.w, w3.x, w3.y, w3.z, w3.w};
        float wk[32];
#pragma unroll
        for (int k = 0; k < 16; ++k) {
            wk[2 * k]     = bf2f((u16)(wa[k] & 0xffffu));
            wk[2 * k + 1] = bf2f((u16)(wa[k] >> 16));
        }
        const float bias = dpb[d0 + dd];
        float accv[8];
#pragma unroll
        for (int tt = 0; tt < 8; ++tt) accv[tt] = bias;
#pragma unroll
        for (int k = 0; k < 32; ++k) {
            const float w = wk[k];
#pragma unroll
            for (int tt = 0; tt < 8; ++tt)
                accv[tt] = fmaf(s_dt[(tq * 8 + tt) * 32 + k], w, accv[tt]);
        }
#pragma unroll
        for (int tt = 0; tt < 8; ++tt)
            s_dl[(tq * 8 + tt) * 64 + dd] = softplus_f(accv[tt]);
    }
    __syncthreads();

    float a[4], h[4];
#pragma unroll
    for (int nj = 0; nj < 4; nj++)
        a[nj] = -__expf(alog[(size_t)d * NSTATE + j * 4 + nj]);

    const size_t chstride = (size_t)DIN * NSTATE;
    const size_t chcol = (size_t)d * NSTATE + j * 4;
    h[0] = h[1] = h[2] = h[3] = 0.f;
    if (PASS) {
        for (int c2 = 0; c2 < c; ++c2) {
            const size_t o = ((size_t)(b * NCHUNK + c2)) * chstride + chcol;
            const float4 Pv = *(const float4*)&P[o];
            const float4 Qv = *(const float4*)&Q[o];
            h[0] = fmaf(Pv.x, h[0], Qv.x);
            h[1] = fmaf(Pv.y, h[1], Qv.y);
            h[2] = fmaf(Pv.z, h[2], Qv.z);
            h[3] = fmaf(Pv.w, h[3], Qv.w);
        }
    }
    const float dskv = PASS ? dsk[d] : 0.f;
    float sdl = 0.f;

    for (int t = 0; t < LCHUNK; t++) {
        const float dl = s_dl[t * 64 + dsub];
        const float xv = s_xs[t * 64 + dsub];
        const float dlx = dl * xv;
        if (!PASS) sdl += dl;
        float yv = 0.f;
#pragma unroll
        for (int nj = 0; nj < 4; nj++) {
            const float bn = s_bc[t * 32 + j * 4 + nj];
            const float dA = __expf(dl * a[nj]);
            h[nj] = fmaf(dA, h[nj], dlx * bn);
            if (PASS) {
                const float cn = s_bc[t * 32 + 16 + j * 4 + nj];
                yv = fmaf(h[nj], cn, yv);
            }
        }
        if (PASS) {
            yv += __shfl_xor(yv, 1);
            yv += __shfl_xor(yv, 2);
            if (j == 0) {
                const float zv = s_z[t * 64 + dsub];
                yb[(rbase + t) * DIN + d] = f2bf((yv + xv * dskv) * silu_f(zv));
            }
        }
    }

    if (!PASS) {
        const size_t o = ((size_t)(b * NCHUNK + c)) * chstride + chcol;
        float4 Pv, Qv;
        Pv.x = __expf(a[0] * sdl); Pv.y = __expf(a[1] * sdl);
        Pv.z = __expf(a[2] * sdl); Pv.w = __expf(a[3] * sdl);
        Qv.x = h[0]; Qv.y = h[1]; Qv.z = h[2]; Qv.w = h[3];
        *(float4*)&P[o] = Pv;
        *(float4*)&Q[o] = Qv;
    }
}

extern "C" void kernel_launch(void* const* d_in, const int* in_sizes, int n_in,
                              void* d_out, int out_size, void* d_ws, size_t ws_size,
                              hipStream_t stream)
{
    const float* feats = (const float*)d_in[0];
    const int*   flens = (const int*)  d_in[1];
    const float* c1w = (const float*)d_in[2];
    const float* c1b = (const float*)d_in[3];
    const float* c2w = (const float*)d_in[4];
    const float* c2b = (const float*)d_in[5];
    const float* nw  = (const float*)d_in[6];
    const float* ipw = (const float*)d_in[7];
    const float* cw  = (const float*)d_in[8];
    const float* cb  = (const float*)d_in[9];
    const float* xpw = (const float*)d_in[10];
    const float* dpw = (const float*)d_in[11];
    const float* dpb = (const float*)d_in[12];
    const float* alog= (const float*)d_in[13];
    const float* dskp= (const float*)d_in[14];
    const float* opw = (const float*)d_in[15];
    const float* hw  = (const float*)d_in[16];
    const float* hb  = (const float*)d_in[17];

    float* ws = (float*)d_ws;
    u16*  XZb    = (u16*)ws;                      // (2048,2048) bf16
    float* X     = ws + 2097152;                  // (2048,512) f32
    u16*  Xb     = (u16*)(ws + 3145728);          // (2048,512) bf16
    u16*  XSb    = (u16*)(ws + 4194304);          // (2048,1024) bf16 ; Y1b alias
    float* P     = ws + 6291456;                  // (4,16,1024,16) f32 = 1M f
    u16*  Yb     = (u16*)(ws + 7340032);          // (2048,1024) bf16
    float* XDBp  = ws + 8388608;                  // 4 x (2048,64) f32
    u16*  ipwTa  = (u16*)(ws + 10125312);         // 8 x (2048,512) bf16 (nw-folded)
    u16*  opwTa  = (u16*)(ws + 14319616);         // 8 x (512,1024) bf16
    u16*  hwT    = (u16*)(ws + 16416768);         // (2048,512) bf16
    u16*  xpwT   = (u16*)(ws + 16941056);         // 8 x (64,1024) bf16
    u16*  dpwT   = (u16*)(ws + 17203200);         // 8 x (1024,32) bf16
    u16*  c1wb   = (u16*)(ws + 17334272);         // (512,256) bf16
    u16*  c2wb   = (u16*)(ws + 17399808);         // (512,1536) bf16
    u16*  Y1b    = XSb;                           // frontend-only alias
    float* logits = (float*)d_out;
    float* Q     = logits;                        // 1M floats of d_out; head overwrites

    // ---------------- fused weight prep (1 dispatch) ----------------
    prep_k<<<17664, 256, 0, stream>>>(hw, hwT, xpw, xpwT, dpw, dpwT,
                                      ipw, ipwTa, nw, opw, opwTa,
                                      c1w, c1wb, c2w, c2wb);

    // ---------------- frontend ----------------
    im2col1_k<<<4096, 256, 0, stream>>>(feats, XZb, flens, logits + (size_t)MROWS * VOCABSZ);
    gemm3_bf16<2, 2, 4, 2, 2, 1><<<dim3(8, 32), 256, 0, stream>>>(
        XZb, 256, c1wb, 256, c1b, nullptr, Y1b, 512, 256, 0);
    im2col2_k<<<12288, 256, 0, stream>>>(Y1b, XZb);
    gemm3_bf16<2, 2, 2, 2, 2, 1><<<dim3(8, 32), 256, 0, stream>>>(
        XZb, 1536, c2wb, 1536, c2b, X, Xb, 512, 1536, 0);

    // ---------------- mamba blocks ----------------
    for (int blk = 0; blk < NB; ++blk) {
        // in_proj: (2048,2048,512), fused RMS row-scale (nw folded in weights)
        gemm3_bf16<2, 2, 4, 2, 7, 1><<<dim3(32, 16), 256, 0, stream>>>(
            Xb, 512, ipwTa + (size_t)blk * 1048576, 512, nullptr,
            nullptr, XZb, 2048, 512, 0);
        dwconv_silu_k<<<dim3(4, MROWS), 256, 0, stream>>>(
            XZb, cw + blk * DIN * 4, cb + blk * DIN, XSb);
        // x_proj: (2048,64,1024) split-K x4 -> partials
        gemm3_bf16<2, 2, 2, 2, 0, 4><<<dim3(1, 32, 4), 256, 0, stream>>>(
            XSb, 1024, xpwT + (size_t)blk * 65536, 1024, nullptr,
            XDBp, nullptr, 64, 1024, 131072);
        // chunked parallel scan with fused dt_proj (2 dispatches)
        scan_chunk_k<0><<<dim3(16, NCHUNK, BATCH), 256, 0, stream>>>(
            XSb, XDBp, nullptr, dpwT + (size_t)blk * 32768, dpb + blk * DIN,
            alog + (size_t)blk * DIN * NSTATE, nullptr, P, Q, nullptr);
        scan_chunk_k<1><<<dim3(16, NCHUNK, BATCH), 256, 0, stream>>>(
            XSb, XDBp, XZb, dpwT + (size_t)blk * 32768, dpb + blk * DIN,
            alog + (size_t)blk * DIN * NSTATE, dskp + blk * DIN, P, Q, Yb);
        // out_proj: (2048,512,1024) + residual -> X f32 + Xb bf16
        gemm3_bf16<2, 2, 2, 2, 4, 1><<<dim3(8, 32), 256, 0, stream>>>(
            Yb, 1024, opwTa + (size_t)blk * 524288, 1024, nullptr,
            X, Xb, 512, 1024, 0);
    }

    // ---------------- head: (2048,2048,512) ----------------
    gemm3_bf16<2, 2, 4, 2, 1, 1><<<dim3(32, 16), 256, 0, stream>>>(
        Xb, 512, hwT, 512, hb, logits, nullptr, 2048, 512, 0);
}

// Round 14
// 808.714 us; speedup vs baseline: 1.5631x; 1.5631x over previous
//
#include <hip/hip_runtime.h>
#include <hip/hip_bf16.h>

#define DMODEL 512
#define NB 8
#define VOCABSZ 2048
#define MEL 80
#define DIN 1024
#define NSTATE 16
#define BATCH 4
#define TIN 2048
#define LL1 1024
#define LSEQ 512
#define MROWS (BATCH*LSEQ)    // 2048
#define M1ROWS (BATCH*LL1)    // 4096
#define NCHUNK 16
#define LCHUNK 32

typedef unsigned short u16;
typedef unsigned int   u32;
typedef __attribute__((ext_vector_type(8))) short short8;
typedef __attribute__((ext_vector_type(4))) float f32x4;

__device__ __forceinline__ float bf2f(u16 v) { return __uint_as_float(((u32)v) << 16); }
__device__ __forceinline__ u16 f2bf(float f) {
    u32 u = __float_as_uint(f);
    return (u16)((u + 0x7fffu + ((u >> 16) & 1u)) >> 16);
}
__device__ __forceinline__ float gelu_exact(float v) {
    return 0.5f * v * (1.0f + erff(v * 0.70710678118654752f));
}
__device__ __forceinline__ float silu_f(float v) { return v / (1.0f + __expf(-v)); }
__device__ __forceinline__ float softplus_f(float v) { return v > 20.f ? v : log1pf(__expf(v)); }

// ---------------------------------------------------------------------------
// bf16 MFMA GEMM, BK=64 as two 32-wide sub-tiles (R12-proven).
// EPI: 0 none, 1 +bias, 2 gelu(+bias), 4 +=Cf residual,
//      7 fused-RMS row-scale (sc from A fragments)
// ---------------------------------------------------------------------------
template<int WM, int WN, int MR, int NR, int EPI, int SPLITK>
__global__ __launch_bounds__(WM*WN*64) void gemm3_bf16(
    const u16* __restrict__ A, int lda,
    const u16* __restrict__ BT, int ldb,
    const float* __restrict__ bias,
    float* __restrict__ Cf, u16* __restrict__ Cb, int ldc,
    int K, int zstride)
{
    constexpr int BM = WM * MR * 16;
    constexpr int BN = WN * NR * 16;
    constexpr int NT = WM * WN * 64;
    constexpr int LA = (BM * 4) / NT;
    constexpr int LB = (BN * 4) / NT;
    __shared__ __align__(16) u16 As[2][2 * BM * 32];
    __shared__ __align__(16) u16 Bs[2][2 * BN * 32];
    __shared__ float s_sc[EPI == 7 ? BM : 1];
    const int tid = threadIdx.x;
    const int m0 = blockIdx.y * BM, n0 = blockIdx.x * BN;
    const int lane = tid & 63;
    const int wave = tid >> 6;
    const int wm = wave / WN, wn = wave % WN;
    const int lr = lane & 15, lk = lane >> 4;

    int kt0 = 0, kend = K;
    if (SPLITK > 1) {
        const int kb = K / SPLITK;
        kt0 = blockIdx.z * kb;
        kend = kt0 + kb;
        Cf += (size_t)blockIdx.z * zstride;
    }

    f32x4 acc[MR][NR];
#pragma unroll
    for (int m = 0; m < MR; ++m)
#pragma unroll
        for (int n = 0; n < NR; ++n) acc[m][n] = (f32x4){0.f, 0.f, 0.f, 0.f};
    float ssq[MR];
#pragma unroll
    for (int m = 0; m < MR; ++m) ssq[m] = 0.f;

    auto stage = [&](int buf, int kt) {
#pragma unroll
        for (int h = 0; h < 2; ++h) {
#pragma unroll
            for (int c = 0; c < LA; ++c) {
                int idx = c * NT + tid;
                const u16* src = A + (size_t)(m0 + (idx >> 2)) * lda + kt + h * 32 + (idx & 3) * 8;
                __builtin_amdgcn_global_load_lds(
                    (const __attribute__((address_space(1))) void*)src,
                    (__attribute__((address_space(3))) void*)&As[buf][h * BM * 32 + idx * 8], 16, 0, 0);
            }
#pragma unroll
            for (int c = 0; c < LB; ++c) {
                int idx = c * NT + tid;
                const u16* src = BT + (size_t)(n0 + (idx >> 2)) * ldb + kt + h * 32 + (idx & 3) * 8;
                __builtin_amdgcn_global_load_lds(
                    (const __attribute__((address_space(1))) void*)src,
                    (__attribute__((address_space(3))) void*)&Bs[buf][h * BN * 32 + idx * 8], 16, 0, 0);
            }
        }
    };

    stage(0, kt0);
    __syncthreads();
    int cur = 0;
    for (int kt = kt0; kt < kend; kt += 64) {
        if (kt + 64 < kend) stage(cur ^ 1, kt + 64);
        short8 a0[MR], a1[MR], b0[NR], b1[NR];
#pragma unroll
        for (int m = 0; m < MR; ++m) {
            a0[m] = *(const short8*)&As[cur][((wm * MR + m) * 16 + lr) * 32 + lk * 8];
            a1[m] = *(const short8*)&As[cur][BM * 32 + ((wm * MR + m) * 16 + lr) * 32 + lk * 8];
        }
#pragma unroll
        for (int n = 0; n < NR; ++n) {
            b0[n] = *(const short8*)&Bs[cur][((wn * NR + n) * 16 + lr) * 32 + lk * 8];
            b1[n] = *(const short8*)&Bs[cur][BN * 32 + ((wn * NR + n) * 16 + lr) * 32 + lk * 8];
        }
        if (EPI == 7 && wn == 0) {
#pragma unroll
            for (int m = 0; m < MR; ++m)
#pragma unroll
                for (int j = 0; j < 8; ++j) {
                    float v0 = bf2f((u16)a0[m][j]);
                    float v1 = bf2f((u16)a1[m][j]);
                    ssq[m] = fmaf(v0, v0, ssq[m]);
                    ssq[m] = fmaf(v1, v1, ssq[m]);
                }
        }
#pragma unroll
        for (int m = 0; m < MR; ++m)
#pragma unroll
            for (int n = 0; n < NR; ++n) {
                acc[m][n] = __builtin_amdgcn_mfma_f32_16x16x32_bf16(a0[m], b0[n], acc[m][n], 0, 0, 0);
                acc[m][n] = __builtin_amdgcn_mfma_f32_16x16x32_bf16(a1[m], b1[n], acc[m][n], 0, 0, 0);
            }
        __syncthreads();
        cur ^= 1;
    }

    if (EPI == 7) {
        if (wn == 0) {
#pragma unroll
            for (int m = 0; m < MR; ++m) {
                float ss = ssq[m];
                ss += __shfl_xor(ss, 16);
                ss += __shfl_xor(ss, 32);
                if (lk == 0)
                    s_sc[(wm * MR + m) * 16 + lr] = rsqrtf(ss * (1.f / 512.f) + 1e-5f);
            }
        }
        __syncthreads();
    }

#pragma unroll
    for (int m = 0; m < MR; ++m) {
#pragma unroll
        for (int n = 0; n < NR; ++n) {
#pragma unroll
            for (int r = 0; r < 4; ++r) {
                const int lrow = (wm * MR + m) * 16 + lk * 4 + r;
                const int row = m0 + lrow;
                const int col = n0 + (wn * NR + n) * 16 + lr;
                float v = acc[m][n][r];
                if (EPI == 1)      v += bias[col];
                else if (EPI == 2) v = gelu_exact(v + bias[col]);
                else if (EPI == 4) v += Cf[(size_t)row * ldc + col];
                else if (EPI == 7) v *= s_sc[lrow];
                if (Cf) Cf[(size_t)row * ldc + col] = v;
                if (Cb) Cb[(size_t)row * ldc + col] = f2bf(v);
            }
        }
    }
}

// ---------------------------------------------------------------------------
// Fused weight prep: all transposes + cast/pads in ONE dispatch (17664 blocks)
// ---------------------------------------------------------------------------
__device__ __forceinline__ void tp_tile(float (*s)[33], const float* __restrict__ in,
                                        u16* __restrict__ out, int R, int C, int tile,
                                        const float* __restrict__ nwp) {
    const int tx = threadIdx.x & 31, ty = threadIdx.x >> 5;
    const int tC = C / 32;
    const int r0 = (tile / tC) * 32, c0 = (tile % tC) * 32;
#pragma unroll
    for (int i = 0; i < 4; ++i)
        s[ty + i * 8][tx] = in[(size_t)(r0 + ty + i * 8) * C + c0 + tx];
    __syncthreads();
    const float nwv = nwp ? nwp[r0 + tx] : 1.f;
#pragma unroll
    for (int i = 0; i < 4; ++i)
        out[(size_t)(c0 + ty + i * 8) * R + r0 + tx] = f2bf(s[tx][ty + i * 8] * nwv);
}

__global__ __launch_bounds__(256) void prep_k(
    const float* __restrict__ hw, u16* __restrict__ hwT,
    const float* __restrict__ xpw, u16* __restrict__ xpwT,
    const float* __restrict__ dpw, u16* __restrict__ dpwT,
    const float* __restrict__ ipw, u16* __restrict__ ipwTa, const float* __restrict__ nw,
    const float* __restrict__ opw, u16* __restrict__ opwTa,
    const float* __restrict__ c1w, u16* __restrict__ c1wb,
    const float* __restrict__ c2w, u16* __restrict__ c2wb)
{
    __shared__ float s[32][33];
    int id = blockIdx.x;
    if (id < 1024) { tp_tile(s, hw, hwT, 512, 2048, id, nullptr); return; }
    id -= 1024;
    if (id < 512) {
        int z = id >> 6, t = id & 63;
        tp_tile(s, xpw + (size_t)z * 65536, xpwT + (size_t)z * 65536, 1024, 64, t, nullptr);
        return;
    }
    id -= 512;
    if (id < 256) {
        int z = id >> 5, t = id & 31;
        tp_tile(s, dpw + (size_t)z * 32768, dpwT + (size_t)z * 32768, 32, 1024, t, nullptr);
        return;
    }
    id -= 256;
    if (id < 8192) {
        int z = id >> 10, t = id & 1023;
        tp_tile(s, ipw + (size_t)z * 1048576, ipwTa + (size_t)z * 1048576, 512, 2048, t, nw + z * DMODEL);
        return;
    }
    id -= 8192;
    if (id < 4096) {
        int z = id >> 9, t = id & 511;
        tp_tile(s, opw + (size_t)z * 524288, opwTa + (size_t)z * 524288, 1024, 512, t, nullptr);
        return;
    }
    id -= 4096;
    if (id < 512) {
        int idx = id * 256 + threadIdx.x;
        int c = idx & 255, r = idx >> 8;
        c1wb[idx] = (c < 240) ? f2bf(c1w[r * 240 + c]) : (u16)0;
        return;
    }
    id -= 512;
    {
        int idx = id * 256 + threadIdx.x;
        c2wb[idx] = f2bf(c2w[idx]);
    }
}

// im2col conv1 -> bf16 (K padded 240->256); also writes out_lens
__global__ void im2col1_k(const float* __restrict__ feats, u16* __restrict__ out,
                          const int* __restrict__ feat_lens, float* __restrict__ lens_out) {
    int idx = blockIdx.x * 256 + threadIdx.x;
    if (blockIdx.x == 0 && threadIdx.x < BATCH) {
        int v = feat_lens[threadIdx.x] / 4;
        if (v < 1) v = 1;
        lens_out[threadIdx.x] = (float)v;
    }
    int c = idx & 255, m = idx >> 8;
    int l1 = m & (LL1 - 1), b = m >> 10;
    float v = 0.f;
    if (c < 240) {
        int ci = c / 3, kk = c - ci * 3;
        int t = 2 * l1 - 1 + kk;
        if (t >= 0 && t < TIN) v = feats[((size_t)b * TIN + t) * MEL + ci];
    }
    out[idx] = f2bf(v);
}

// im2col conv2: bf16 in, bf16 out (2048,1536)
__global__ void im2col2_k(const u16* __restrict__ y1b, u16* __restrict__ out) {
    int idx = blockIdx.x * 256 + threadIdx.x;
    int c = idx % 1536, m = idx / 1536;
    int l = m & (LSEQ - 1), b = m >> 9;
    int ci = c / 3, kk = c - ci * 3;
    int t = 2 * l - 1 + kk;
    out[idx] = (t >= 0 && t < LL1) ? y1b[((size_t)b * LL1 + t) * 512 + ci] : (u16)0;
}

// causal depthwise conv (K=4) + bias + SiLU; bf16 in, bf16 out
__global__ __launch_bounds__(256) void dwconv_silu_k(const u16* __restrict__ xzb,
                                                     const float* __restrict__ cw,
                                                     const float* __restrict__ cb,
                                                     u16* __restrict__ xsb) {
    int d = blockIdx.x * 256 + threadIdx.x;
    int m = blockIdx.y;
    int l = m & (LSEQ - 1);
    int b = m >> 9;
    float acc = cb[d];
    const float4 w4 = *reinterpret_cast<const float4*>(&cw[d * 4]);
    const float wk[4] = {w4.x, w4.y, w4.z, w4.w};
#pragma unroll
    for (int k = 0; k < 4; k++) {
        int t = l - 3 + k;
        if (t >= 0) acc += wk[k] * bf2f(xzb[((size_t)(b * LSEQ + t)) * (2 * DIN) + d]);
    }
    xsb[(size_t)m * DIN + d] = f2bf(silu_f(acc));
}

// ---------------------------------------------------------------------------
// dt_proj single-shot (R11/R12-proven): A = sum of 4 split-K partials (dt cols
// 0..31), K=32, one MFMA per acc; softplus(+dpb) -> DELb. BM=128 BN=64.
// ---------------------------------------------------------------------------
__global__ __launch_bounds__(256) void dtproj_k(
    const float* __restrict__ part, const u16* __restrict__ dpwT,
    const float* __restrict__ dpb, u16* __restrict__ delb)
{
    __shared__ __align__(16) u16 As[128 * 32];
    __shared__ __align__(16) u16 Bs[64 * 32];
    const int tid = threadIdx.x;
    const int m0 = blockIdx.y * 128, n0 = blockIdx.x * 64;
    {
        const int r = tid >> 1, hh = (tid & 1) * 16;
        const size_t o = (size_t)(m0 + r) * 64 + hh;
        float4 s[4];
#pragma unroll
        for (int q = 0; q < 4; ++q) {
            s[q] = *(const float4*)&part[o + q * 4];
#pragma unroll
            for (int p = 1; p < 4; ++p) {
                const float4 v = *(const float4*)&part[(size_t)p * 131072 + o + q * 4];
                s[q].x += v.x; s[q].y += v.y; s[q].z += v.z; s[q].w += v.w;
            }
        }
        u32 pk[8];
#pragma unroll
        for (int q = 0; q < 4; ++q) {
            pk[2 * q]     = (u32)f2bf(s[q].x) | ((u32)f2bf(s[q].y) << 16);
            pk[2 * q + 1] = (u32)f2bf(s[q].z) | ((u32)f2bf(s[q].w) << 16);
        }
        *(uint4*)&As[r * 32 + hh]     = make_uint4(pk[0], pk[1], pk[2], pk[3]);
        *(uint4*)&As[r * 32 + hh + 8] = make_uint4(pk[4], pk[5], pk[6], pk[7]);
    }
    {
        const int row = tid >> 2, p4 = (tid & 3) * 8;
        const u16* src = dpwT + (size_t)(n0 + row) * 32 + p4;
        __builtin_amdgcn_global_load_lds(
            (const __attribute__((address_space(1))) void*)src,
            (__attribute__((address_space(3))) void*)&Bs[row * 32 + p4], 16, 0, 0);
    }
    __syncthreads();
    const int lane = tid & 63, wave = tid >> 6;
    const int wm = wave >> 1, wn = wave & 1;
    const int lr = lane & 15, lk = lane >> 4;
    short8 b8[2];
#pragma unroll
    for (int n = 0; n < 2; ++n)
        b8[n] = *(const short8*)&Bs[((wn * 2 + n) * 16 + lr) * 32 + lk * 8];
#pragma unroll
    for (int m = 0; m < 4; ++m) {
        const short8 a8 = *(const short8*)&As[((wm * 4 + m) * 16 + lr) * 32 + lk * 8];
#pragma unroll
        for (int n = 0; n < 2; ++n) {
            f32x4 acc = __builtin_amdgcn_mfma_f32_16x16x32_bf16(a8, b8[n], (f32x4){0.f,0.f,0.f,0.f}, 0, 0, 0);
#pragma unroll
            for (int r = 0; r < 4; ++r) {
                const int row = m0 + (wm * 4 + m) * 16 + lk * 4 + r;
                const int col = n0 + (wn * 2 + n) * 16 + lr;
                delb[(size_t)row * DIN + col] = f2bf(softplus_f(acc[r] + dpb[col]));
            }
        }
    }
}

// ---------------------------------------------------------------------------
// Chunked parallel scan (R12-proven: NCHUNK=16, LCHUNK=32, DELb input).
// B/C staged by summing the 4 split-K partials. PASS0: emit P,Q.
// PASS1: in-kernel <=15-step combine, seeded scan, fused epilogue -> y bf16.
// ---------------------------------------------------------------------------
template<int PASS>
__global__ __launch_bounds__(256) void scan_chunk_k(
    const u16* __restrict__ deltab, const u16* __restrict__ xsb,
    const float* __restrict__ part, const u16* __restrict__ xzb,
    const float* __restrict__ alog, const float* __restrict__ dsk,
    float* __restrict__ P, float* __restrict__ Q,
    u16* __restrict__ yb)
{
    __shared__ float s_bc[LCHUNK * 32];
    __shared__ float s_dl[LCHUNK * 64];
    __shared__ float s_xs[LCHUNK * 64];
    __shared__ float s_z [PASS ? LCHUNK * 64 : 1];

    const int tid  = threadIdx.x;
    const int j    = tid & 3;
    const int dsub = tid >> 2;
    const int d0   = blockIdx.x * 64;
    const int c    = blockIdx.y;
    const int b    = blockIdx.z;
    const int d    = d0 + dsub;
    const size_t rbase = (size_t)b * LSEQ + c * LCHUNK;

    for (int idx = tid; idx < LCHUNK * 32; idx += 256) {
        int t = idx >> 5, cc = idx & 31;
        const size_t o = (rbase + t) * 64 + 32 + cc;
        s_bc[idx] = part[o] + part[131072 + o] + part[262144 + o] + part[393216 + o];
    }
    for (int idx = tid; idx < LCHUNK * 64; idx += 256) {
        int t = idx >> 6, dd = idx & 63;
        s_dl[idx] = bf2f(deltab[(rbase + t) * DIN + d0 + dd]);
        s_xs[idx] = bf2f(xsb[(rbase + t) * DIN + d0 + dd]);
        if (PASS) s_z[idx] = bf2f(xzb[(rbase + t) * (2 * DIN) + DIN + d0 + dd]);
    }
    __syncthreads();

    float a[4], h[4];
#pragma unroll
    for (int nj = 0; nj < 4; nj++)
        a[nj] = -__expf(alog[(size_t)d * NSTATE + j * 4 + nj]);

    const size_t chstride = (size_t)DIN * NSTATE;
    const size_t chcol = (size_t)d * NSTATE + j * 4;
    h[0] = h[1] = h[2] = h[3] = 0.f;
    if (PASS) {
        for (int c2 = 0; c2 < c; ++c2) {
            const size_t o = ((size_t)(b * NCHUNK + c2)) * chstride + chcol;
            const float4 Pv = *(const float4*)&P[o];
            const float4 Qv = *(const float4*)&Q[o];
            h[0] = fmaf(Pv.x, h[0], Qv.x);
            h[1] = fmaf(Pv.y, h[1], Qv.y);
            h[2] = fmaf(Pv.z, h[2], Qv.z);
            h[3] = fmaf(Pv.w, h[3], Qv.w);
        }
    }
    const float dskv = PASS ? dsk[d] : 0.f;
    float sdl = 0.f;

    for (int t = 0; t < LCHUNK; t++) {
        const float dl = s_dl[t * 64 + dsub];
        const float xv = s_xs[t * 64 + dsub];
        const float dlx = dl * xv;
        if (!PASS) sdl += dl;
        float yv = 0.f;
#pragma unroll
        for (int nj = 0; nj < 4; nj++) {
            const float bn = s_bc[t * 32 + j * 4 + nj];
            const float dA = __expf(dl * a[nj]);
            h[nj] = fmaf(dA, h[nj], dlx * bn);
            if (PASS) {
                const float cn = s_bc[t * 32 + 16 + j * 4 + nj];
                yv = fmaf(h[nj], cn, yv);
            }
        }
        if (PASS) {
            yv += __shfl_xor(yv, 1);
            yv += __shfl_xor(yv, 2);
            if (j == 0) {
                const float zv = s_z[t * 64 + dsub];
                yb[(rbase + t) * DIN + d] = f2bf((yv + xv * dskv) * silu_f(zv));
            }
        }
    }

    if (!PASS) {
        const size_t o = ((size_t)(b * NCHUNK + c)) * chstride + chcol;
        float4 Pv, Qv;
        Pv.x = __expf(a[0] * sdl); Pv.y = __expf(a[1] * sdl);
        Pv.z = __expf(a[2] * sdl); Pv.w = __expf(a[3] * sdl);
        Qv.x = h[0]; Qv.y = h[1]; Qv.z = h[2]; Qv.w = h[3];
        *(float4*)&P[o] = Pv;
        *(float4*)&Q[o] = Qv;
    }
}

extern "C" void kernel_launch(void* const* d_in, const int* in_sizes, int n_in,
                              void* d_out, int out_size, void* d_ws, size_t ws_size,
                              hipStream_t stream)
{
    const float* feats = (const float*)d_in[0];
    const int*   flens = (const int*)  d_in[1];
    const float* c1w = (const float*)d_in[2];
    const float* c1b = (const float*)d_in[3];
    const float* c2w = (const float*)d_in[4];
    const float* c2b = (const float*)d_in[5];
    const float* nw  = (const float*)d_in[6];
    const float* ipw = (const float*)d_in[7];
    const float* cw  = (const float*)d_in[8];
    const float* cb  = (const float*)d_in[9];
    const float* xpw = (const float*)d_in[10];
    const float* dpw = (const float*)d_in[11];
    const float* dpb = (const float*)d_in[12];
    const float* alog= (const float*)d_in[13];
    const float* dskp= (const float*)d_in[14];
    const float* opw = (const float*)d_in[15];
    const float* hw  = (const float*)d_in[16];
    const float* hb  = (const float*)d_in[17];

    float* ws = (float*)d_ws;
    u16*  XZb    = (u16*)ws;                      // (2048,2048) bf16
    float* X     = ws + 2097152;                  // (2048,512) f32
    u16*  Xb     = (u16*)(ws + 3145728);          // (2048,512) bf16
    u16*  XSb    = (u16*)(ws + 4194304);          // (2048,1024) bf16 ; Y1b alias
    u16*  DELb   = (u16*)(ws + 5242880);          // (2048,1024) bf16
    float* P     = ws + 6291456;                  // (4,16,1024,16) f32 = 1M f
    u16*  Yb     = (u16*)(ws + 7340032);          // (2048,1024) bf16
    float* XDBp  = ws + 8388608;                  // 4 x (2048,64) f32
    u16*  ipwTa  = (u16*)(ws + 10125312);         // 8 x (2048,512) bf16 (nw-folded)
    u16*  opwTa  = (u16*)(ws + 14319616);         // 8 x (512,1024) bf16
    u16*  hwT    = (u16*)(ws + 16416768);         // (2048,512) bf16
    u16*  xpwT   = (u16*)(ws + 16941056);         // 8 x (64,1024) bf16
    u16*  dpwT   = (u16*)(ws + 17203200);         // 8 x (1024,32) bf16
    u16*  c1wb   = (u16*)(ws + 17334272);         // (512,256) bf16
    u16*  c2wb   = (u16*)(ws + 17399808);         // (512,1536) bf16
    u16*  Y1b    = XSb;                           // frontend-only alias
    float* logits = (float*)d_out;
    float* Q     = logits;                        // 1M floats of d_out; head overwrites

    // ---------------- fused weight prep (1 dispatch) ----------------
    prep_k<<<17664, 256, 0, stream>>>(hw, hwT, xpw, xpwT, dpw, dpwT,
                                      ipw, ipwTa, nw, opw, opwTa,
                                      c1w, c1wb, c2w, c2wb);

    // ---------------- frontend ----------------
    im2col1_k<<<4096, 256, 0, stream>>>(feats, XZb, flens, logits + (size_t)MROWS * VOCABSZ);
    gemm3_bf16<2, 2, 4, 2, 2, 1><<<dim3(8, 32), 256, 0, stream>>>(
        XZb, 256, c1wb, 256, c1b, nullptr, Y1b, 512, 256, 0);
    im2col2_k<<<12288, 256, 0, stream>>>(Y1b, XZb);
    gemm3_bf16<2, 2, 2, 2, 2, 1><<<dim3(8, 32), 256, 0, stream>>>(
        XZb, 1536, c2wb, 1536, c2b, X, Xb, 512, 1536, 0);

    // ---------------- mamba blocks ----------------
    for (int blk = 0; blk < NB; ++blk) {
        // in_proj: (2048,2048,512), fused RMS row-scale (nw folded in weights)
        gemm3_bf16<2, 2, 4, 2, 7, 1><<<dim3(32, 16), 256, 0, stream>>>(
            Xb, 512, ipwTa + (size_t)blk * 1048576, 512, nullptr,
            nullptr, XZb, 2048, 512, 0);
        dwconv_silu_k<<<dim3(4, MROWS), 256, 0, stream>>>(
            XZb, cw + blk * DIN * 4, cb + blk * DIN, XSb);
        // x_proj: (2048,64,1024) split-K x4 -> partials
        gemm3_bf16<2, 2, 2, 2, 0, 4><<<dim3(1, 32, 4), 256, 0, stream>>>(
            XSb, 1024, xpwT + (size_t)blk * 65536, 1024, nullptr,
            XDBp, nullptr, 64, 1024, 131072);
        // dt_proj single-shot from partials
        dtproj_k<<<dim3(16, 16), 256, 0, stream>>>(
            XDBp, dpwT + (size_t)blk * 32768, dpb + blk * DIN, DELb);
        // chunked parallel scan (2 dispatches, B/C summed from partials)
        scan_chunk_k<0><<<dim3(16, NCHUNK, BATCH), 256, 0, stream>>>(
            DELb, XSb, XDBp, nullptr, alog + (size_t)blk * DIN * NSTATE,
            nullptr, P, Q, nullptr);
        scan_chunk_k<1><<<dim3(16, NCHUNK, BATCH), 256, 0, stream>>>(
            DELb, XSb, XDBp, XZb, alog + (size_t)blk * DIN * NSTATE,
            dskp + blk * DIN, P, Q, Yb);
        // out_proj: (2048,512,1024) + residual -> X f32 + Xb bf16
        gemm3_bf16<2, 2, 2, 2, 4, 1><<<dim3(8, 32), 256, 0, stream>>>(
            Yb, 1024, opwTa + (size_t)blk * 524288, 1024, nullptr,
            X, Xb, 512, 1024, 0);
    }

    // ---------------- head: (2048,2048,512) ----------------
    gemm3_bf16<2, 2, 4, 2, 1, 1><<<dim3(32, 16), 256, 0, stream>>>(
        Xb, 512, hwT, 512, hb, logits, nullptr, 2048, 512, 0);
}

// Round 15
// 782.192 us; speedup vs baseline: 1.6161x; 1.0339x over previous
//
#include <hip/hip_runtime.h>
#include <hip/hip_bf16.h>

#define DMODEL 512
#define NB 8
#define VOCABSZ 2048
#define MEL 80
#define DIN 1024
#define NSTATE 16
#define BATCH 4
#define TIN 2048
#define LL1 1024
#define LSEQ 512
#define MROWS (BATCH*LSEQ)    // 2048
#define M1ROWS (BATCH*LL1)    // 4096
#define NCHUNK 16
#define LCHUNK 32

typedef unsigned short u16;
typedef unsigned int   u32;
typedef __attribute__((ext_vector_type(8))) short short8;
typedef __attribute__((ext_vector_type(4))) float f32x4;

__device__ __forceinline__ float bf2f(u16 v) { return __uint_as_float(((u32)v) << 16); }
__device__ __forceinline__ u16 f2bf(float f) {
    u32 u = __float_as_uint(f);
    return (u16)((u + 0x7fffu + ((u >> 16) & 1u)) >> 16);
}
__device__ __forceinline__ float gelu_exact(float v) {
    return 0.5f * v * (1.0f + erff(v * 0.70710678118654752f));
}
__device__ __forceinline__ float silu_f(float v) { return v / (1.0f + __expf(-v)); }
__device__ __forceinline__ float softplus_f(float v) { return v > 20.f ? v : log1pf(__expf(v)); }

// ---------------------------------------------------------------------------
// bf16 MFMA GEMM, BK=64 as two 32-wide sub-tiles (R12/R14-proven).
// EPI: 0 none, 1 +bias, 2 gelu(+bias), 4 +=Cf residual,
//      7 fused-RMS row-scale (sc from A fragments)
// ---------------------------------------------------------------------------
template<int WM, int WN, int MR, int NR, int EPI, int SPLITK>
__global__ __launch_bounds__(WM*WN*64) void gemm3_bf16(
    const u16* __restrict__ A, int lda,
    const u16* __restrict__ BT, int ldb,
    const float* __restrict__ bias,
    float* __restrict__ Cf, u16* __restrict__ Cb, int ldc,
    int K, int zstride)
{
    constexpr int BM = WM * MR * 16;
    constexpr int BN = WN * NR * 16;
    constexpr int NT = WM * WN * 64;
    constexpr int LA = (BM * 4) / NT;
    constexpr int LB = (BN * 4) / NT;
    __shared__ __align__(16) u16 As[2][2 * BM * 32];
    __shared__ __align__(16) u16 Bs[2][2 * BN * 32];
    __shared__ float s_sc[EPI == 7 ? BM : 1];
    const int tid = threadIdx.x;
    const int m0 = blockIdx.y * BM, n0 = blockIdx.x * BN;
    const int lane = tid & 63;
    const int wave = tid >> 6;
    const int wm = wave / WN, wn = wave % WN;
    const int lr = lane & 15, lk = lane >> 4;

    int kt0 = 0, kend = K;
    if (SPLITK > 1) {
        const int kb = K / SPLITK;
        kt0 = blockIdx.z * kb;
        kend = kt0 + kb;
        Cf += (size_t)blockIdx.z * zstride;
    }

    f32x4 acc[MR][NR];
#pragma unroll
    for (int m = 0; m < MR; ++m)
#pragma unroll
        for (int n = 0; n < NR; ++n) acc[m][n] = (f32x4){0.f, 0.f, 0.f, 0.f};
    float ssq[MR];
#pragma unroll
    for (int m = 0; m < MR; ++m) ssq[m] = 0.f;

    auto stage = [&](int buf, int kt) {
#pragma unroll
        for (int h = 0; h < 2; ++h) {
#pragma unroll
            for (int c = 0; c < LA; ++c) {
                int idx = c * NT + tid;
                const u16* src = A + (size_t)(m0 + (idx >> 2)) * lda + kt + h * 32 + (idx & 3) * 8;
                __builtin_amdgcn_global_load_lds(
                    (const __attribute__((address_space(1))) void*)src,
                    (__attribute__((address_space(3))) void*)&As[buf][h * BM * 32 + idx * 8], 16, 0, 0);
            }
#pragma unroll
            for (int c = 0; c < LB; ++c) {
                int idx = c * NT + tid;
                const u16* src = BT + (size_t)(n0 + (idx >> 2)) * ldb + kt + h * 32 + (idx & 3) * 8;
                __builtin_amdgcn_global_load_lds(
                    (const __attribute__((address_space(1))) void*)src,
                    (__attribute__((address_space(3))) void*)&Bs[buf][h * BN * 32 + idx * 8], 16, 0, 0);
            }
        }
    };

    stage(0, kt0);
    __syncthreads();
    int cur = 0;
    for (int kt = kt0; kt < kend; kt += 64) {
        if (kt + 64 < kend) stage(cur ^ 1, kt + 64);
        short8 a0[MR], a1[MR], b0[NR], b1[NR];
#pragma unroll
        for (int m = 0; m < MR; ++m) {
            a0[m] = *(const short8*)&As[cur][((wm * MR + m) * 16 + lr) * 32 + lk * 8];
            a1[m] = *(const short8*)&As[cur][BM * 32 + ((wm * MR + m) * 16 + lr) * 32 + lk * 8];
        }
#pragma unroll
        for (int n = 0; n < NR; ++n) {
            b0[n] = *(const short8*)&Bs[cur][((wn * NR + n) * 16 + lr) * 32 + lk * 8];
            b1[n] = *(const short8*)&Bs[cur][BN * 32 + ((wn * NR + n) * 16 + lr) * 32 + lk * 8];
        }
        if (EPI == 7 && wn == 0) {
#pragma unroll
            for (int m = 0; m < MR; ++m)
#pragma unroll
                for (int j = 0; j < 8; ++j) {
                    float v0 = bf2f((u16)a0[m][j]);
                    float v1 = bf2f((u16)a1[m][j]);
                    ssq[m] = fmaf(v0, v0, ssq[m]);
                    ssq[m] = fmaf(v1, v1, ssq[m]);
                }
        }
#pragma unroll
        for (int m = 0; m < MR; ++m)
#pragma unroll
            for (int n = 0; n < NR; ++n) {
                acc[m][n] = __builtin_amdgcn_mfma_f32_16x16x32_bf16(a0[m], b0[n], acc[m][n], 0, 0, 0);
                acc[m][n] = __builtin_amdgcn_mfma_f32_16x16x32_bf16(a1[m], b1[n], acc[m][n], 0, 0, 0);
            }
        __syncthreads();
        cur ^= 1;
    }

    if (EPI == 7) {
        if (wn == 0) {
#pragma unroll
            for (int m = 0; m < MR; ++m) {
                float ss = ssq[m];
                ss += __shfl_xor(ss, 16);
                ss += __shfl_xor(ss, 32);
                if (lk == 0)
                    s_sc[(wm * MR + m) * 16 + lr] = rsqrtf(ss * (1.f / 512.f) + 1e-5f);
            }
        }
        __syncthreads();
    }

#pragma unroll
    for (int m = 0; m < MR; ++m) {
#pragma unroll
        for (int n = 0; n < NR; ++n) {
#pragma unroll
            for (int r = 0; r < 4; ++r) {
                const int lrow = (wm * MR + m) * 16 + lk * 4 + r;
                const int row = m0 + lrow;
                const int col = n0 + (wn * NR + n) * 16 + lr;
                float v = acc[m][n][r];
                if (EPI == 1)      v += bias[col];
                else if (EPI == 2) v = gelu_exact(v + bias[col]);
                else if (EPI == 4) v += Cf[(size_t)row * ldc + col];
                else if (EPI == 7) v *= s_sc[lrow];
                if (Cf) Cf[(size_t)row * ldc + col] = v;
                if (Cb) Cb[(size_t)row * ldc + col] = f2bf(v);
            }
        }
    }
}

// ---------------------------------------------------------------------------
// Fused weight prep: all transposes + cast/pads in ONE dispatch (R14-proven)
// ---------------------------------------------------------------------------
__device__ __forceinline__ void tp_tile(float (*s)[33], const float* __restrict__ in,
                                        u16* __restrict__ out, int R, int C, int tile,
                                        const float* __restrict__ nwp) {
    const int tx = threadIdx.x & 31, ty = threadIdx.x >> 5;
    const int tC = C / 32;
    const int r0 = (tile / tC) * 32, c0 = (tile % tC) * 32;
#pragma unroll
    for (int i = 0; i < 4; ++i)
        s[ty + i * 8][tx] = in[(size_t)(r0 + ty + i * 8) * C + c0 + tx];
    __syncthreads();
    const float nwv = nwp ? nwp[r0 + tx] : 1.f;
#pragma unroll
    for (int i = 0; i < 4; ++i)
        out[(size_t)(c0 + ty + i * 8) * R + r0 + tx] = f2bf(s[tx][ty + i * 8] * nwv);
}

__global__ __launch_bounds__(256) void prep_k(
    const float* __restrict__ hw, u16* __restrict__ hwT,
    const float* __restrict__ xpw, u16* __restrict__ xpwT,
    const float* __restrict__ dpw, u16* __restrict__ dpwT,
    const float* __restrict__ ipw, u16* __restrict__ ipwTa, const float* __restrict__ nw,
    const float* __restrict__ opw, u16* __restrict__ opwTa,
    const float* __restrict__ c1w, u16* __restrict__ c1wb,
    const float* __restrict__ c2w, u16* __restrict__ c2wb)
{
    __shared__ float s[32][33];
    int id = blockIdx.x;
    if (id < 1024) { tp_tile(s, hw, hwT, 512, 2048, id, nullptr); return; }
    id -= 1024;
    if (id < 512) {
        int z = id >> 6, t = id & 63;
        tp_tile(s, xpw + (size_t)z * 65536, xpwT + (size_t)z * 65536, 1024, 64, t, nullptr);
        return;
    }
    id -= 512;
    if (id < 256) {
        int z = id >> 5, t = id & 31;
        tp_tile(s, dpw + (size_t)z * 32768, dpwT + (size_t)z * 32768, 32, 1024, t, nullptr);
        return;
    }
    id -= 256;
    if (id < 8192) {
        int z = id >> 10, t = id & 1023;
        tp_tile(s, ipw + (size_t)z * 1048576, ipwTa + (size_t)z * 1048576, 512, 2048, t, nw + z * DMODEL);
        return;
    }
    id -= 8192;
    if (id < 4096) {
        int z = id >> 9, t = id & 511;
        tp_tile(s, opw + (size_t)z * 524288, opwTa + (size_t)z * 524288, 1024, 512, t, nullptr);
        return;
    }
    id -= 4096;
    if (id < 512) {
        int idx = id * 256 + threadIdx.x;
        int c = idx & 255, r = idx >> 8;
        c1wb[idx] = (c < 240) ? f2bf(c1w[r * 240 + c]) : (u16)0;
        return;
    }
    id -= 512;
    {
        int idx = id * 256 + threadIdx.x;
        c2wb[idx] = f2bf(c2w[idx]);
    }
}

// im2col conv1 -> bf16 (K padded 240->256); also writes out_lens
__global__ void im2col1_k(const float* __restrict__ feats, u16* __restrict__ out,
                          const int* __restrict__ feat_lens, float* __restrict__ lens_out) {
    int idx = blockIdx.x * 256 + threadIdx.x;
    if (blockIdx.x == 0 && threadIdx.x < BATCH) {
        int v = feat_lens[threadIdx.x] / 4;
        if (v < 1) v = 1;
        lens_out[threadIdx.x] = (float)v;
    }
    int c = idx & 255, m = idx >> 8;
    int l1 = m & (LL1 - 1), b = m >> 10;
    float v = 0.f;
    if (c < 240) {
        int ci = c / 3, kk = c - ci * 3;
        int t = 2 * l1 - 1 + kk;
        if (t >= 0 && t < TIN) v = feats[((size_t)b * TIN + t) * MEL + ci];
    }
    out[idx] = f2bf(v);
}

// im2col conv2: bf16 in, bf16 out (2048,1536)
__global__ void im2col2_k(const u16* __restrict__ y1b, u16* __restrict__ out) {
    int idx = blockIdx.x * 256 + threadIdx.x;
    int c = idx % 1536, m = idx / 1536;
    int l = m & (LSEQ - 1), b = m >> 9;
    int ci = c / 3, kk = c - ci * 3;
    int t = 2 * l - 1 + kk;
    out[idx] = (t >= 0 && t < LL1) ? y1b[((size_t)b * LL1 + t) * 512 + ci] : (u16)0;
}

// causal depthwise conv (K=4) + bias + SiLU; bf16 in, bf16 out
__global__ __launch_bounds__(256) void dwconv_silu_k(const u16* __restrict__ xzb,
                                                     const float* __restrict__ cw,
                                                     const float* __restrict__ cb,
                                                     u16* __restrict__ xsb) {
    int d = blockIdx.x * 256 + threadIdx.x;
    int m = blockIdx.y;
    int l = m & (LSEQ - 1);
    int b = m >> 9;
    float acc = cb[d];
    const float4 w4 = *reinterpret_cast<const float4*>(&cw[d * 4]);
    const float wk[4] = {w4.x, w4.y, w4.z, w4.w};
#pragma unroll
    for (int k = 0; k < 4; k++) {
        int t = l - 3 + k;
        if (t >= 0) acc += wk[k] * bf2f(xzb[((size_t)(b * LSEQ + t)) * (2 * DIN) + d]);
    }
    xsb[(size_t)m * DIN + d] = f2bf(silu_f(acc));
}

// ---------------------------------------------------------------------------
// Chunked parallel scan with MFMA-fused dt_proj.
// Staging: B/C + dt(bf16) summed from the 4 split-K partials; dpw 64x32 slice
// via global_load_lds.  Then delta = softplus(dt @ dpw^T + dpb) as 2 MFMAs
// per wave -> s_dl fp32.  PASS0: emit P,Q.  PASS1: <=15-step combine, seeded
// scan, fused +xs*D / *silu(z) epilogue -> y bf16.
// ---------------------------------------------------------------------------
template<int PASS>
__global__ __launch_bounds__(256) void scan_chunk_k(
    const u16* __restrict__ xsb, const float* __restrict__ part,
    const u16* __restrict__ xzb,
    const u16* __restrict__ dpwT, const float* __restrict__ dpb,
    const float* __restrict__ alog, const float* __restrict__ dsk,
    float* __restrict__ P, float* __restrict__ Q,
    u16* __restrict__ yb)
{
    __shared__ float s_bc[LCHUNK * 32];
    __shared__ __align__(16) u16 s_dtb[LCHUNK * 32];  // dt bf16, 2 KB
    __shared__ __align__(16) u16 s_dpw[64 * 32];      // dpw slice, 4 KB
    __shared__ float s_dl[LCHUNK * 64];
    __shared__ float s_xs[LCHUNK * 64];
    __shared__ float s_z [PASS ? LCHUNK * 64 : 1];

    const int tid  = threadIdx.x;
    const int j    = tid & 3;
    const int dsub = tid >> 2;
    const int d0   = blockIdx.x * 64;
    const int c    = blockIdx.y;
    const int b    = blockIdx.z;
    const int d    = d0 + dsub;
    const size_t rbase = (size_t)b * LSEQ + c * LCHUNK;

    // dpw slice: rows d0..d0+63, all 32 k -> 4 KB contiguous
    {
        const u16* src = dpwT + (size_t)d0 * 32 + tid * 8;
        __builtin_amdgcn_global_load_lds(
            (const __attribute__((address_space(1))) void*)src,
            (__attribute__((address_space(3))) void*)&s_dpw[tid * 8], 16, 0, 0);
    }
    for (int idx = tid; idx < LCHUNK * 32; idx += 256) {
        int t = idx >> 5, cc = idx & 31;
        const size_t o = (rbase + t) * 64 + cc;
        s_dtb[idx] = f2bf(part[o] + part[131072 + o] + part[262144 + o] + part[393216 + o]);
        const size_t o2 = o + 32;
        s_bc[idx] = part[o2] + part[131072 + o2] + part[262144 + o2] + part[393216 + o2];
    }
    for (int idx = tid; idx < LCHUNK * 64; idx += 256) {
        int t = idx >> 6, dd = idx & 63;
        s_xs[idx] = bf2f(xsb[(rbase + t) * DIN + d0 + dd]);
        if (PASS) s_z[idx] = bf2f(xzb[(rbase + t) * (2 * DIN) + DIN + d0 + dd]);
    }
    __syncthreads();

    // dt_proj: wave w -> d cols [w*16, w*16+16); 2 MFMAs (t 0..15, 16..31)
    {
        const int lane = tid & 63, w = tid >> 6;
        const int lr = lane & 15, lk = lane >> 4;
        const short8 a0 = *(const short8*)&s_dtb[lr * 32 + lk * 8];
        const short8 a1 = *(const short8*)&s_dtb[(16 + lr) * 32 + lk * 8];
        const short8 bf = *(const short8*)&s_dpw[(w * 16 + lr) * 32 + lk * 8];
        f32x4 c0 = __builtin_amdgcn_mfma_f32_16x16x32_bf16(a0, bf, (f32x4){0.f,0.f,0.f,0.f}, 0, 0, 0);
        f32x4 c1 = __builtin_amdgcn_mfma_f32_16x16x32_bf16(a1, bf, (f32x4){0.f,0.f,0.f,0.f}, 0, 0, 0);
        const int dcol = w * 16 + lr;               // C/D: col=lane&15
        const float bias = dpb[d0 + dcol];
#pragma unroll
        for (int r = 0; r < 4; ++r) {               // C/D: row=(lane>>4)*4+r
            s_dl[(lk * 4 + r) * 64 + dcol]        = softplus_f(c0[r] + bias);
            s_dl[(16 + lk * 4 + r) * 64 + dcol]   = softplus_f(c1[r] + bias);
        }
    }
    __syncthreads();

    float a[4], h[4];
#pragma unroll
    for (int nj = 0; nj < 4; nj++)
        a[nj] = -__expf(alog[(size_t)d * NSTATE + j * 4 + nj]);

    const size_t chstride = (size_t)DIN * NSTATE;
    const size_t chcol = (size_t)d * NSTATE + j * 4;
    h[0] = h[1] = h[2] = h[3] = 0.f;
    if (PASS) {
        for (int c2 = 0; c2 < c; ++c2) {
            const size_t o = ((size_t)(b * NCHUNK + c2)) * chstride + chcol;
            const float4 Pv = *(const float4*)&P[o];
            const float4 Qv = *(const float4*)&Q[o];
            h[0] = fmaf(Pv.x, h[0], Qv.x);
            h[1] = fmaf(Pv.y, h[1], Qv.y);
            h[2] = fmaf(Pv.z, h[2], Qv.z);
            h[3] = fmaf(Pv.w, h[3], Qv.w);
        }
    }
    const float dskv = PASS ? dsk[d] : 0.f;
    float sdl = 0.f;

    for (int t = 0; t < LCHUNK; t++) {
        const float dl = s_dl[t * 64 + dsub];
        const float xv = s_xs[t * 64 + dsub];
        const float dlx = dl * xv;
        if (!PASS) sdl += dl;
        float yv = 0.f;
#pragma unroll
        for (int nj = 0; nj < 4; nj++) {
            const float bn = s_bc[t * 32 + j * 4 + nj];
            const float dA = __expf(dl * a[nj]);
            h[nj] = fmaf(dA, h[nj], dlx * bn);
            if (PASS) {
                const float cn = s_bc[t * 32 + 16 + j * 4 + nj];
                yv = fmaf(h[nj], cn, yv);
            }
        }
        if (PASS) {
            yv += __shfl_xor(yv, 1);
            yv += __shfl_xor(yv, 2);
            if (j == 0) {
                const float zv = s_z[t * 64 + dsub];
                yb[(rbase + t) * DIN + d] = f2bf((yv + xv * dskv) * silu_f(zv));
            }
        }
    }

    if (!PASS) {
        const size_t o = ((size_t)(b * NCHUNK + c)) * chstride + chcol;
        float4 Pv, Qv;
        Pv.x = __expf(a[0] * sdl); Pv.y = __expf(a[1] * sdl);
        Pv.z = __expf(a[2] * sdl); Pv.w = __expf(a[3] * sdl);
        Qv.x = h[0]; Qv.y = h[1]; Qv.z = h[2]; Qv.w = h[3];
        *(float4*)&P[o] = Pv;
        *(float4*)&Q[o] = Qv;
    }
}

extern "C" void kernel_launch(void* const* d_in, const int* in_sizes, int n_in,
                              void* d_out, int out_size, void* d_ws, size_t ws_size,
                              hipStream_t stream)
{
    const float* feats = (const float*)d_in[0];
    const int*   flens = (const int*)  d_in[1];
    const float* c1w = (const float*)d_in[2];
    const float* c1b = (const float*)d_in[3];
    const float* c2w = (const float*)d_in[4];
    const float* c2b = (const float*)d_in[5];
    const float* nw  = (const float*)d_in[6];
    const float* ipw = (const float*)d_in[7];
    const float* cw  = (const float*)d_in[8];
    const float* cb  = (const float*)d_in[9];
    const float* xpw = (const float*)d_in[10];
    const float* dpw = (const float*)d_in[11];
    const float* dpb = (const float*)d_in[12];
    const float* alog= (const float*)d_in[13];
    const float* dskp= (const float*)d_in[14];
    const float* opw = (const float*)d_in[15];
    const float* hw  = (const float*)d_in[16];
    const float* hb  = (const float*)d_in[17];

    float* ws = (float*)d_ws;
    u16*  XZb    = (u16*)ws;                      // (2048,2048) bf16
    float* X     = ws + 2097152;                  // (2048,512) f32
    u16*  Xb     = (u16*)(ws + 3145728);          // (2048,512) bf16
    u16*  XSb    = (u16*)(ws + 4194304);          // (2048,1024) bf16 ; Y1b alias
    float* P     = ws + 6291456;                  // (4,16,1024,16) f32 = 1M f
    u16*  Yb     = (u16*)(ws + 7340032);          // (2048,1024) bf16
    float* XDBp  = ws + 8388608;                  // 4 x (2048,64) f32
    u16*  ipwTa  = (u16*)(ws + 10125312);         // 8 x (2048,512) bf16 (nw-folded)
    u16*  opwTa  = (u16*)(ws + 14319616);         // 8 x (512,1024) bf16
    u16*  hwT    = (u16*)(ws + 16416768);         // (2048,512) bf16
    u16*  xpwT   = (u16*)(ws + 16941056);         // 8 x (64,1024) bf16
    u16*  dpwT   = (u16*)(ws + 17203200);         // 8 x (1024,32) bf16
    u16*  c1wb   = (u16*)(ws + 17334272);         // (512,256) bf16
    u16*  c2wb   = (u16*)(ws + 17399808);         // (512,1536) bf16
    u16*  Y1b    = XSb;                           // frontend-only alias
    float* logits = (float*)d_out;
    float* Q     = logits;                        // 1M floats of d_out; head overwrites

    // ---------------- fused weight prep (1 dispatch) ----------------
    prep_k<<<17664, 256, 0, stream>>>(hw, hwT, xpw, xpwT, dpw, dpwT,
                                      ipw, ipwTa, nw, opw, opwTa,
                                      c1w, c1wb, c2w, c2wb);

    // ---------------- frontend ----------------
    im2col1_k<<<4096, 256, 0, stream>>>(feats, XZb, flens, logits + (size_t)MROWS * VOCABSZ);
    gemm3_bf16<2, 2, 4, 2, 2, 1><<<dim3(8, 32), 256, 0, stream>>>(
        XZb, 256, c1wb, 256, c1b, nullptr, Y1b, 512, 256, 0);
    im2col2_k<<<12288, 256, 0, stream>>>(Y1b, XZb);
    gemm3_bf16<2, 2, 2, 2, 2, 1><<<dim3(8, 32), 256, 0, stream>>>(
        XZb, 1536, c2wb, 1536, c2b, X, Xb, 512, 1536, 0);

    // ---------------- mamba blocks ----------------
    for (int blk = 0; blk < NB; ++blk) {
        // in_proj: (2048,2048,512), fused RMS row-scale (nw folded in weights)
        gemm3_bf16<2, 2, 4, 2, 7, 1><<<dim3(32, 16), 256, 0, stream>>>(
            Xb, 512, ipwTa + (size_t)blk * 1048576, 512, nullptr,
            nullptr, XZb, 2048, 512, 0);
        dwconv_silu_k<<<dim3(4, MROWS), 256, 0, stream>>>(
            XZb, cw + blk * DIN * 4, cb + blk * DIN, XSb);
        // x_proj: (2048,64,1024) split-K x4 -> partials
        gemm3_bf16<2, 2, 2, 2, 0, 4><<<dim3(1, 32, 4), 256, 0, stream>>>(
            XSb, 1024, xpwT + (size_t)blk * 65536, 1024, nullptr,
            XDBp, nullptr, 64, 1024, 131072);
        // chunked parallel scan with MFMA-fused dt_proj (2 dispatches)
        scan_chunk_k<0><<<dim3(16, NCHUNK, BATCH), 256, 0, stream>>>(
            XSb, XDBp, nullptr, dpwT + (size_t)blk * 32768, dpb + blk * DIN,
            alog + (size_t)blk * DIN * NSTATE, nullptr, P, Q, nullptr);
        scan_chunk_k<1><<<dim3(16, NCHUNK, BATCH), 256, 0, stream>>>(
            XSb, XDBp, XZb, dpwT + (size_t)blk * 32768, dpb + blk * DIN,
            alog + (size_t)blk * DIN * NSTATE, dskp + blk * DIN, P, Q, Yb);
        // out_proj: (2048,512,1024) + residual -> X f32 + Xb bf16
        gemm3_bf16<2, 2, 2, 2, 4, 1><<<dim3(8, 32), 256, 0, stream>>>(
            Yb, 1024, opwTa + (size_t)blk * 524288, 1024, nullptr,
            X, Xb, 512, 1024, 0);
    }

    // ---------------- head: (2048,2048,512) ----------------
    gemm3_bf16<2, 2, 4, 2, 1, 1><<<dim3(32, 16), 256, 0, stream>>>(
        Xb, 512, hwT, 512, hb, logits, nullptr, 2048, 512, 0);
}